// Round 22
// baseline (1348.879 us; speedup 1.0000x reference)
//
#include <hip/hip_runtime.h>

typedef __attribute__((ext_vector_type(8))) short short8;
typedef __attribute__((ext_vector_type(4))) float f32x4;
typedef __attribute__((ext_vector_type(16))) float f32x16;
typedef __attribute__((ext_vector_type(4))) unsigned short us4;
typedef __attribute__((ext_vector_type(8))) unsigned short us8;

union FragU { short8 s; us4 h[2]; us8 u; };

__device__ __forceinline__ unsigned short f2bf(float f) {
  union { float f; unsigned int u; } v; v.f = f;
  unsigned int r = (v.u + 0x7fffu + ((v.u >> 16) & 1u)) >> 16;
  return (unsigned short)r;
}

typedef const __attribute__((address_space(1))) unsigned int* gas1_t;
typedef __attribute__((address_space(3))) unsigned int* las3_t;
__device__ __forceinline__ void glds16(const void* g, void* l) {
  __builtin_amdgcn_global_load_lds((gas1_t)g, (las3_t)l, 16, 0, 0);
}

// ---------------- prep: transpose sf [B][C][HW] fp32 -> PADDED Xtp [B][202*202][C] bf16
__global__ void transpose_pad_k(const float* __restrict__ sf, unsigned short* __restrict__ Xtp) {
  __shared__ float tile[32][33];
  int b = blockIdx.z, c0 = blockIdx.y * 32, p0 = blockIdx.x * 32;
  int tx = threadIdx.x, ty = threadIdx.y;
#pragma unroll
  for (int i = 0; i < 4; ++i)
    tile[ty + i * 8][tx] = sf[((size_t)(b * 256 + c0 + ty + i * 8) * 40000) + p0 + tx];
  __syncthreads();
#pragma unroll
  for (int i = 0; i < 4; ++i) {
    int p = p0 + ty + i * 8;
    int y = p / 200, x = p - y * 200;
    size_t pf = (size_t)b * 40804 + (size_t)(y + 1) * 202 + (x + 1);
    Xtp[(pf << 8) + c0 + tx] = f2bf(tile[tx][ty + i * 8]);
  }
}

// ---------------- prep: fold BN into w1 -> W1f[h][oc][k], k = tap*256+c (bf16, K-contig)
__global__ void prep_w1f_k(const float* __restrict__ w1, const float* __restrict__ gamma,
                           const float* __restrict__ var, unsigned short* __restrict__ W1f) {
  int id = blockIdx.x * 256 + threadIdx.x;
  if (id >= 6 * 256 * 2304) return;
  int k = id % 2304;
  int rest = id / 2304;
  int oc = rest & 255, h = rest >> 8;
  int tap = k >> 8, c = k & 255;
  int hc = h * 256 + oc;
  float s = gamma[hc] * rsqrtf(var[hc] + 1e-5f);
  W1f[id] = f2bf(s * w1[(hc * 256 + c) * 9 + tap]);
}

// ---------------- PRIMARY v8: v6/v7 structure (R20-verified: single barrier, counted
// vmcnt 6/0, 3-buffer rotation, XOR swizzle) with the MFMA shape switched to
// 32x32x16 (µbench 2382-2495 TF vs 2075 for 16x16x32 — 17% higher pipe rate, half the
// instruction count). Wave tile 64x128 = 2x4 tiles of 32x32, acc f32x16[2][4].
// A/B frag: row/col = lane&31, k = (lane>>5)*8+j.  D: col=lane&31,
// row=(reg&3)+8*(reg>>2)+4*(lane>>5)  [m74/m101-verified].
__global__ __launch_bounds__(256, 2) void conv_head_v8_k(
    const unsigned short* __restrict__ Xtp, const unsigned short* __restrict__ W1f,
    const float* __restrict__ gamma, const float* __restrict__ beta,
    const float* __restrict__ mean, const float* __restrict__ var,
    const float* __restrict__ w2, const float* __restrict__ b2,
    float* __restrict__ out) {
  const int NOUT[6] = {4, 2, 1, 3, 2, 2};
  const int OFFS[6] = {0, 4, 6, 7, 10, 12};
  __shared__ __align__(16) char smem[73728];
  unsigned short* h_s = (unsigned short*)smem;

  int tid = threadIdx.x;
  int head = blockIdx.z, b = blockIdx.y;
  int p_loc = blockIdx.x * 128;
  int nout = NOUT[head], ooff = OFFS[head];

  int wid = tid >> 6, lane = tid & 63;
  int wm = wid >> 1, wn = wid & 1;          // 2m x 2n wave grid, wave tile 64px x 128oc
  int l15 = lane & 15, lhi = lane >> 4;
  int l31 = lane & 31, khi = lane >> 5;     // 32x32 frag coords

  // A source: thread -> rows r0=tid>>2 and r0+64; SWIZZLED 16B chunk (R18-verified):
  int r0 = tid >> 2;
  int cbsw = (((tid & 3) ^ ((tid >> 3) & 3)) << 4);
  int pA0 = p_loc + r0;       if (pA0 > 39999) pA0 = 39999;
  int pA1 = p_loc + r0 + 64;  if (pA1 > 39999) pA1 = 39999;
  int ay0 = pA0 / 200, ax0 = pA0 - ay0 * 200;
  int ay1 = pA1 / 200, ax1 = pA1 - ay1 * 200;
  const char* xb = (const char*)Xtp + (size_t)b * 40804 * 512;
  const char* As0 = xb + (size_t)((ay0 + 1) * 202 + ax0 + 1) * 512 + cbsw;
  const char* As1 = xb + (size_t)((ay1 + 1) * 202 + ax1 + 1) * 512 + cbsw;

  // B source: rows r0 + {0,64,128,192} of head's W1f, same swizzled chunk
  const char* Bs0 = (const char*)W1f + (size_t)(head * 256 + r0) * 4608 + cbsw;
  const char* Bs1 = Bs0 + (size_t)64 * 4608;
  const char* Bs2 = Bs0 + (size_t)128 * 4608;
  const char* Bs3 = Bs0 + (size_t)192 * 4608;

  // rotating staging buffers
  char* rA = smem;            // read target (tile kt)
  char* rB = smem + 24576;    // tile kt+1
  char* rC = smem + 49152;    // stage target (tile kt+2)

  auto STAGE = [&](int kn, char* dst) {
    int tap = kn >> 3;
    int c0b = (kn & 7) << 6;
    int t3 = tap / 3;
    int doff = (t3 - 1) * 202 + (tap - t3 * 3 - 1);
    long ab = (long)doff * 512 + c0b;
    long bb = (long)kn * 64;
    glds16(As0 + ab, dst + wid * 1024);
    glds16(As1 + ab, dst + wid * 1024 + 4096);
    glds16(Bs0 + bb, dst + 8192 + wid * 1024);
    glds16(Bs1 + bb, dst + 8192 + wid * 1024 + 4096);
    glds16(Bs2 + bb, dst + 8192 + wid * 1024 + 8192);
    glds16(Bs3 + bb, dst + 8192 + wid * 1024 + 12288);
  };

  f32x16 acc32[2][4];
#pragma unroll
  for (int mi = 0; mi < 2; ++mi)
#pragma unroll
    for (int ni = 0; ni < 4; ++ni)
#pragma unroll
      for (int r = 0; r < 16; ++r) acc32[mi][ni][r] = 0.f;

  // prologue: tiles 0 and 1 in flight (12 loads) — no wait yet
  STAGE(0, rA);
  STAGE(1, rB);

  // frag-read granule swizzle: granule g of row r holds global granule g ^ ((r>>1)&3).
  // Row within 32-tile is l31; tile offsets are multiples of 32 -> (row>>1)&3 == (l31>>1)&3.
  int gsw = (l31 >> 1) & 3;

  for (int kt = 0; kt < 72; ++kt) {
    // counted wait: tile kt retired (queue at most [kt(6), kt+1(6)])
    if (kt < 71) asm volatile("s_waitcnt vmcnt(6)" ::: "memory");
    else         asm volatile("s_waitcnt vmcnt(0)" ::: "memory");
    __builtin_amdgcn_sched_barrier(0);
    __builtin_amdgcn_s_barrier();          // single barrier: buf(kt) visible to all;
    __builtin_amdgcn_sched_barrier(0);     // also gates restage of buf(kt-1) below

    if (kt < 70) STAGE(kt + 2, rC);        // rC == buffer read at kt-1: safe post-barrier

    const unsigned short* A_sh = (const unsigned short*)rA;
    const unsigned short* B_sh = (const unsigned short*)(rA + 8192);
    // frags: a32[mi2][kh], b32[ni2][kh]; granule index = kh*2 + khi, swizzled by gsw
    short8 a32[2][2], b32[4][2];
#pragma unroll
    for (int mi = 0; mi < 2; ++mi)
#pragma unroll
      for (int kh = 0; kh < 2; ++kh) {
        int g = (kh * 2 + khi) ^ gsw;
        FragU u;
        u.u = *(const us8*)&A_sh[(wm * 64 + mi * 32 + l31) * 32 + g * 8];
        a32[mi][kh] = u.s;
      }
#pragma unroll
    for (int ni = 0; ni < 4; ++ni)
#pragma unroll
      for (int kh = 0; kh < 2; ++kh) {
        int g = (kh * 2 + khi) ^ gsw;
        FragU u;
        u.u = *(const us8*)&B_sh[(wn * 128 + ni * 32 + l31) * 32 + g * 8];
        b32[ni][kh] = u.s;
      }
    __builtin_amdgcn_s_setprio(1);
#pragma unroll
    for (int kh = 0; kh < 2; ++kh)
#pragma unroll
      for (int mi = 0; mi < 2; ++mi)
#pragma unroll
        for (int ni = 0; ni < 4; ++ni)
          acc32[mi][ni] = __builtin_amdgcn_mfma_f32_32x32x16_bf16(a32[mi][kh], b32[ni][kh], acc32[mi][ni], 0, 0, 0);
    __builtin_amdgcn_s_setprio(0);

    char* t = rA; rA = rB; rB = rC; rC = t;
  }

  // ---- epilogue: relu(acc + tb) in fp32 regs; w2 frags into regs;
  //      h -> LDS bf16 [128][264] via the 32x32 D-layout; 1x1 via 16x16 MFMA (verified).
  {
    float tbr[4];
#pragma unroll
    for (int ni = 0; ni < 4; ++ni) {
      int hc = head * 256 + wn * 128 + ni * 32 + l31;
      float s = gamma[hc] * rsqrtf(var[hc] + 1e-5f);
      tbr[ni] = beta[hc] - s * mean[hc];
    }
#pragma unroll
    for (int mi = 0; mi < 2; ++mi)
#pragma unroll
      for (int ni = 0; ni < 4; ++ni)
#pragma unroll
        for (int r = 0; r < 16; ++r)
          acc32[mi][ni][r] = fmaxf(acc32[mi][ni][r] + tbr[ni], 0.f);
  }
  short8 wfr[8];
  {
    int jr = (l15 < nout) ? (ooff + l15) : 0;
    const float* wrow = w2 + jr * 256;
#pragma unroll
    for (int kc = 0; kc < 8; ++kc) {
      int koff = kc * 32 + lhi * 8;
      FragU u;
#pragma unroll
      for (int q = 0; q < 8; ++q) u.u[q] = f2bf(wrow[koff + q]);
      wfr[kc] = u.s;
    }
  }
  __syncthreads();   // all waves done with last tile's frag reads before h_s overwrite
#pragma unroll
  for (int mi = 0; mi < 2; ++mi) {
#pragma unroll
    for (int ni = 0; ni < 4; ++ni) {
      int ocl = wn * 128 + ni * 32 + l31;
#pragma unroll
      for (int r = 0; r < 16; ++r) {
        int px = wm * 64 + mi * 32 + (r & 3) + 8 * (r >> 2) + 4 * khi;
        h_s[px * 264 + ocl] = f2bf(acc32[mi][ni][r]);
      }
    }
  }
  __syncthreads();

#pragma unroll
  for (int g2 = 0; g2 < 2; ++g2) {
    int grp = wid * 2 + g2;
    float b2v = (l15 < nout) ? b2[ooff + l15] : 0.f;
    f32x4 oacc = (f32x4){0.f, 0.f, 0.f, 0.f};
#pragma unroll
    for (int kc = 0; kc < 8; ++kc) {
      int koff = kc * 32 + lhi * 8;
      FragU hu;
      hu.u = *(const us8*)&h_s[(grp * 16 + l15) * 264 + koff];
      oacc = __builtin_amdgcn_mfma_f32_16x16x32_bf16(hu.s, wfr[kc], oacc, 0, 0, 0);
    }
    if (l15 < nout) {
      float* dst = out + (size_t)(b * 29 + ooff + l15) * 40000;
#pragma unroll
      for (int r = 0; r < 4; ++r) {
        int px_g = p_loc + grp * 16 + lhi * 4 + r;
        if (px_g < 40000) dst[px_g] = oacc[r] + b2v;
      }
    }
  }
}

// ---------------- FALLBACK (R10-proven, no ws): B folded in-kernel from w1
__global__ __launch_bounds__(512) void conv_head_nows_k(
    const float* __restrict__ sf, const float* __restrict__ w1,
    const float* __restrict__ gamma, const float* __restrict__ beta,
    const float* __restrict__ mean, const float* __restrict__ var,
    const float* __restrict__ w2, const float* __restrict__ b2,
    float* __restrict__ out) {
  const int NOUT[6] = {4, 2, 1, 3, 2, 2};
  const int OFFS[6] = {0, 4, 6, 7, 10, 12};
  __shared__ __align__(16) char smem[78080];
  unsigned short* A_s  = (unsigned short*)smem;
  unsigned short* B_s  = (unsigned short*)(smem + 9216);
  unsigned short* h_s  = (unsigned short*)smem;
  unsigned short* w2_s = (unsigned short*)(smem + 67584);
  float* tb_s          = (float*)(smem + 76032);
  float* s_s           = (float*)(smem + 77056);

  int tid = threadIdx.x;
  int head = blockIdx.z, b = blockIdx.y;
  int p_loc = blockIdx.x * 128;
  int nout = NOUT[head], ooff = OFFS[head];
  {
    int j = tid >> 5, c8 = (tid & 31) * 8;
    us8 t;
#pragma unroll
    for (int q = 0; q < 8; ++q)
      t[q] = (j < nout) ? f2bf(w2[(ooff + j) * 256 + c8 + q]) : (unsigned short)0;
    *(us8*)&w2_s[j * 264 + c8] = t;
  }
  if (tid < 256) {
    int hc = head * 256 + tid;
    float s = gamma[hc] * rsqrtf(var[hc] + 1e-5f);
    s_s[tid] = s;
    tb_s[tid] = beta[hc] - s * mean[hc];
  }
  __syncthreads();

  int wid = tid >> 6, lane = tid & 63;
  int wm = wid >> 2, wn = wid & 3;
  int l15 = lane & 15, lhi = lane >> 4;
  int cg = wid, mm = lane;
  int p0 = p_loc + mm, p1 = p0 + 64;
  int ay0 = p0 / 200, ax0 = p0 - ay0 * 200;
  int ay1 = p1 / 200, ax1 = p1 - ay1 * 200;
  const float* sfb = sf + (size_t)b * 256 * 40000;
  int oc = tid >> 1, half = tid & 1;
  const float* w1h = w1 + ((size_t)head * 256 + oc) * 2304;
  float sv = s_s[oc];

  f32x4 acc[4][4];
#pragma unroll
  for (int mi = 0; mi < 4; ++mi)
#pragma unroll
    for (int ni = 0; ni < 4; ++ni) acc[mi][ni] = (f32x4){0.f, 0.f, 0.f, 0.f};

  for (int kt = 0; kt < 72; ++kt) {
    int tap = kt >> 3;
    int c0 = (kt & 7) << 5;
    int t3 = tap / 3;
    int dy = t3 - 1, dx = tap - t3 * 3 - 1;
    {
      const float* src = sfb + (size_t)(c0 + cg * 4) * 40000;
      int yy = ay0 + dy, xx = ax0 + dx;
      us4 v = (us4){0, 0, 0, 0};
      if ((unsigned)yy < 200u && (unsigned)xx < 200u) {
        int pix = yy * 200 + xx;
        v[0] = f2bf(src[pix]);
        v[1] = f2bf(src[40000 + pix]);
        v[2] = f2bf(src[80000 + pix]);
        v[3] = f2bf(src[120000 + pix]);
      }
      *(us4*)&A_s[mm * 36 + cg * 4] = v;
      yy = ay1 + dy; xx = ax1 + dx;
      us4 w = (us4){0, 0, 0, 0};
      if ((unsigned)yy < 200u && (unsigned)xx < 200u) {
        int pix = yy * 200 + xx;
        w[0] = f2bf(src[pix]);
        w[1] = f2bf(src[40000 + pix]);
        w[2] = f2bf(src[80000 + pix]);
        w[3] = f2bf(src[120000 + pix]);
      }
      *(us4*)&A_s[(mm + 64) * 36 + cg * 4] = w;
    }
    {
      int kk = half * 16;
#pragma unroll
      for (int g = 0; g < 4; ++g) {
        us4 t;
#pragma unroll
        for (int q = 0; q < 4; ++q)
          t[q] = f2bf(sv * w1h[(c0 + kk + g * 4 + q) * 9 + tap]);
        *(us4*)&B_s[oc * 36 + kk + g * 4] = t;
      }
    }
    __syncthreads();
    short8 af[4], bfr[4];
#pragma unroll
    for (int mi = 0; mi < 4; ++mi) {
      int a = (wm * 64 + mi * 16 + l15) * 36 + lhi * 8;
      FragU u;
      u.h[0] = *(const us4*)&A_s[a];
      u.h[1] = *(const us4*)&A_s[a + 4];
      af[mi] = u.s;
    }
#pragma unroll
    for (int ni = 0; ni < 4; ++ni) {
      int a = (wn * 64 + ni * 16 + l15) * 36 + lhi * 8;
      FragU u;
      u.h[0] = *(const us4*)&B_s[a];
      u.h[1] = *(const us4*)&B_s[a + 4];
      bfr[ni] = u.s;
    }
#pragma unroll
    for (int mi = 0; mi < 4; ++mi)
#pragma unroll
      for (int ni = 0; ni < 4; ++ni)
        acc[mi][ni] = __builtin_amdgcn_mfma_f32_16x16x32_bf16(af[mi], bfr[ni], acc[mi][ni], 0, 0, 0);
    __syncthreads();
  }
#pragma unroll
  for (int mi = 0; mi < 4; ++mi) {
#pragma unroll
    for (int ni = 0; ni < 4; ++ni) {
      int ocl = wn * 64 + ni * 16 + l15;
      float tbv = tb_s[ocl];
#pragma unroll
      for (int r = 0; r < 4; ++r) {
        int px = wm * 64 + mi * 16 + lhi * 4 + r;
        float v = fmaxf(acc[mi][ni][r] + tbv, 0.f);
        h_s[px * 264 + ocl] = f2bf(v);
      }
    }
  }
  __syncthreads();
  {
    int j = l15;
    float b2v = (j < nout) ? b2[ooff + j] : 0.f;
    f32x4 oacc = (f32x4){0.f, 0.f, 0.f, 0.f};
#pragma unroll
    for (int kc = 0; kc < 8; ++kc) {
      int koff = kc * 32 + lhi * 8;
      FragU hu, wu;
      hu.u = *(const us8*)&h_s[(wid * 16 + l15) * 264 + koff];
      wu.u = *(const us8*)&w2_s[l15 * 264 + koff];
      oacc = __builtin_amdgcn_mfma_f32_16x16x32_bf16(hu.s, wu.s, oacc, 0, 0, 0);
    }
    if (j < nout) {
      float* dst = out + (size_t)(b * 29 + ooff + j) * 40000;
#pragma unroll
      for (int r = 0; r < 4; ++r) {
        int px_g = p_loc + wid * 16 + lhi * 4 + r;
        if (px_g < 40000) dst[px_g] = oacc[r] + b2v;
      }
    }
  }
}

// ---------------- targets: heatmap + zero scalar channels (validated)
__global__ void heat_k(const float* __restrict__ gt, float* __restrict__ out) {
  __shared__ float bx[128], by[128], binv[128];
  __shared__ int bcls[128];
  int b = blockIdx.y, tid = threadIdx.x;
  if (tid < 128) {
    const float* g = gt + (b * 128 + tid) * 10;
    float x = g[0], y = g[1], z = g[2];
    bool valid = fabsf(x) + fabsf(y) + fabsf(z) > 0.f;
    float gx = x / 0.1f;
    float gy = (y + 39.68f) / 0.1f;
    float fx = floorf(gx), fy = floorf(gy);
    int gxi = (int)fx, gyi = (int)fy;
    valid = valid && gxi >= 0 && gxi < 200 && gyi >= 0 && gyi < 200;
    float bw = g[3], bl = g[4];
    float sigma = fmaxf(sqrtf(bw * bw + bl * bl) * 0.5f, 2.0f) / 3.0f;
    binv[tid] = valid ? 1.f / (2.f * sigma * sigma) : -1.f;
    bx[tid] = fx;
    by[tid] = fy;
    bcls[tid] = min(max((int)g[7], 0), 3);
  }
  __syncthreads();
  int pid = blockIdx.x * 256 + tid;
  if (pid >= 40000) return;
  float py = (float)(pid / 200);
  float px = (float)(pid - (pid / 200) * 200);
  float h0 = 0.f, h1 = 0.f, h2 = 0.f, h3 = 0.f;
  for (int n = 0; n < 128; ++n) {
    float inv = binv[n];
    if (inv < 0.f) continue;
    float ddx = px - bx[n], ddy = py - by[n];
    float t = (ddx * ddx + ddy * ddy) * inv;
    if (t > 40.f) continue;
    float e = __expf(-t);
    int c = bcls[n];
    h0 = fmaxf(h0, c == 0 ? e : 0.f);
    h1 = fmaxf(h1, c == 1 ? e : 0.f);
    h2 = fmaxf(h2, c == 2 ? e : 0.f);
    h3 = fmaxf(h3, c == 3 ? e : 0.f);
  }
  int base = (b * 29 + 14) * 40000 + pid;
  out[base] = h0;
  out[base + 40000] = h1;
  out[base + 80000] = h2;
  out[base + 120000] = h3;
#pragma unroll
  for (int q = 0; q < 11; ++q) out[base + (4 + q) * 40000] = 0.f;
}

// ---------------- targets: serial per-batch scatter (validated)
__global__ void scatter_k(const float* __restrict__ gt, float* __restrict__ out) {
  int b = threadIdx.x;
  if (b >= 4) return;
  for (int n = 0; n < 128; ++n) {
    const float* g = gt + (b * 128 + n) * 10;
    float x = g[0], y = g[1], z = g[2];
    if (!(fabsf(x) + fabsf(y) + fabsf(z) > 0.f)) continue;
    float gx = x / 0.1f;
    float gy = (y + 39.68f) / 0.1f;
    float fx = floorf(gx), fy = floorf(gy);
    int gxi = (int)fx, gyi = (int)fy;
    if (gxi < 0 || gxi >= 200 || gyi < 0 || gyi >= 200) continue;
    int base = (b * 29 + 18) * 40000 + gyi * 200 + gxi;
    out[base] = gx - fx;
    out[base + 1 * 40000] = gy - fy;
    out[base + 2 * 40000] = z;
    out[base + 3 * 40000] = g[3];
    out[base + 4 * 40000] = g[4];
    out[base + 5 * 40000] = g[5];
    out[base + 6 * 40000] = sinf(g[6]);
    out[base + 7 * 40000] = cosf(g[6]);
    out[base + 8 * 40000] = g[8];
    out[base + 9 * 40000] = g[9];
    out[base + 10 * 40000] = 1.f;
  }
}

extern "C" void kernel_launch(void* const* d_in, const int* in_sizes, int n_in,
                              void* d_out, int out_size, void* d_ws, size_t ws_size,
                              hipStream_t stream) {
  const float* sf    = (const float*)d_in[0];
  const float* gt    = (const float*)d_in[1];
  const float* w1    = (const float*)d_in[2];
  const float* gamma = (const float*)d_in[3];
  const float* beta  = (const float*)d_in[4];
  const float* mean  = (const float*)d_in[5];
  const float* var   = (const float*)d_in[6];
  const float* w2    = (const float*)d_in[7];
  const float* b2    = (const float*)d_in[8];
  float* out = (float*)d_out;
  char* ws = (char*)d_ws;

  const size_t W1F_BYTES = (size_t)6 * 256 * 2304 * 2;        //  7,077,888
  const size_t XTP_BYTES = (size_t)4 * 40804 * 256 * 2;       // 83,566,592
  unsigned short* W1f = (unsigned short*)ws;

  dim3 cgrid(313, 4, 6);
  if (ws_size >= W1F_BYTES + XTP_BYTES) {
    unsigned short* Xtp = (unsigned short*)(ws + W1F_BYTES);
    prep_w1f_k<<<(6 * 256 * 2304 + 255) / 256, 256, 0, stream>>>(w1, gamma, var, W1f);
    hipMemsetAsync(Xtp, 0, XTP_BYTES, stream);
    transpose_pad_k<<<dim3(1250, 8, 4), dim3(32, 8), 0, stream>>>(sf, Xtp);
    conv_head_v8_k<<<cgrid, 256, 0, stream>>>(Xtp, W1f, gamma, beta, mean, var, w2, b2, out);
  } else {
    conv_head_nows_k<<<cgrid, 512, 0, stream>>>(sf, w1, gamma, beta, mean, var, w2, b2, out);
  }
  heat_k<<<dim3(157, 4), 256, 0, stream>>>(gt, out);
  scatter_k<<<1, 64, 0, stream>>>(gt, out);
}

// Round 23
// 1210.350 us; speedup vs baseline: 1.1145x; 1.1145x over previous
//
#include <hip/hip_runtime.h>

typedef __attribute__((ext_vector_type(8))) short short8;
typedef __attribute__((ext_vector_type(4))) float f32x4;
typedef __attribute__((ext_vector_type(4))) unsigned short us4;
typedef __attribute__((ext_vector_type(8))) unsigned short us8;

union FragU { short8 s; us4 h[2]; us8 u; };

__device__ __forceinline__ unsigned short f2bf(float f) {
  union { float f; unsigned int u; } v; v.f = f;
  unsigned int r = (v.u + 0x7fffu + ((v.u >> 16) & 1u)) >> 16;
  return (unsigned short)r;
}

typedef const __attribute__((address_space(1))) unsigned int* gas1_t;
typedef __attribute__((address_space(3))) unsigned int* las3_t;
__device__ __forceinline__ void glds16(const void* g, void* l) {
  __builtin_amdgcn_global_load_lds((gas1_t)g, (las3_t)l, 16, 0, 0);
}

// ---------------- prep: transpose sf [B][C][HW] fp32 -> PADDED Xtp interior
__global__ void transpose_pad_k(const float* __restrict__ sf, unsigned short* __restrict__ Xtp) {
  __shared__ float tile[32][33];
  int b = blockIdx.z, c0 = blockIdx.y * 32, p0 = blockIdx.x * 32;
  int tx = threadIdx.x, ty = threadIdx.y;
#pragma unroll
  for (int i = 0; i < 4; ++i)
    tile[ty + i * 8][tx] = sf[((size_t)(b * 256 + c0 + ty + i * 8) * 40000) + p0 + tx];
  __syncthreads();
#pragma unroll
  for (int i = 0; i < 4; ++i) {
    int p = p0 + ty + i * 8;
    int y = p / 200, x = p - y * 200;
    size_t pf = (size_t)b * 40804 + (size_t)(y + 1) * 202 + (x + 1);
    Xtp[(pf << 8) + c0 + tx] = f2bf(tile[tx][ty + i * 8]);
  }
}

// ---------------- prep: zero ONLY the 804 border pixels per batch (replaces 83.5MB memset)
__global__ void border_zero_k(unsigned short* __restrict__ Xtp) {
  int t = blockIdx.x * 256 + threadIdx.x;   // (b, border-pixel p, ch8): 4*804*32
  if (t >= 4 * 804 * 32) return;
  int ch8 = t & 31;
  int rest = t >> 5;
  int p = rest % 804, b = rest / 804;
  int y, x;
  if (p < 202)      { y = 0;           x = p; }
  else if (p < 404) { y = 201;         x = p - 202; }
  else if (p < 604) { y = p - 404 + 1; x = 0; }
  else              { y = p - 604 + 1; x = 201; }
  size_t pf = (size_t)b * 40804 + (size_t)y * 202 + x;
  *(us8*)&Xtp[(pf << 8) + ch8 * 8] = (us8){0, 0, 0, 0, 0, 0, 0, 0};
}

// ---------------- prep: fold BN into w1 -> W1f[h][oc][k], k = tap*256+c (bf16, K-contig)
__global__ void prep_w1f_k(const float* __restrict__ w1, const float* __restrict__ gamma,
                           const float* __restrict__ var, unsigned short* __restrict__ W1f) {
  int id = blockIdx.x * 256 + threadIdx.x;
  if (id >= 6 * 256 * 2304) return;
  int k = id % 2304;
  int rest = id / 2304;
  int oc = rest & 255, h = rest >> 8;
  int tap = k >> 8, c = k & 255;
  int hc = h * 256 + oc;
  float s = gamma[hc] * rsqrtf(var[hc] + 1e-5f);
  W1f[id] = f2bf(s * w1[(hc * 256 + c) * 9 + tap]);
}

// ---------------- PRIMARY v6 (R20-verified optimum): 128px x 256oc, 4 waves, wave tile
// 64x128 (acc[4][8]), XOR slot-swizzle, 3-buffer glds pipeline, single barrier/K-step,
// counted vmcnt 6/0, setprio around MFMA cluster. MfmaUtil ~47% = this structure's
// measured ceiling (R19-R22: barrier-halving, interleave, and 32x32 shape all null/neg).
__global__ __launch_bounds__(256, 2) void conv_head_v6_k(
    const unsigned short* __restrict__ Xtp, const unsigned short* __restrict__ W1f,
    const float* __restrict__ gamma, const float* __restrict__ beta,
    const float* __restrict__ mean, const float* __restrict__ var,
    const float* __restrict__ w2, const float* __restrict__ b2,
    float* __restrict__ out) {
  const int NOUT[6] = {4, 2, 1, 3, 2, 2};
  const int OFFS[6] = {0, 4, 6, 7, 10, 12};
  __shared__ __align__(16) char smem[73728];
  unsigned short* h_s = (unsigned short*)smem;

  int tid = threadIdx.x;
  int head = blockIdx.z, b = blockIdx.y;
  int p_loc = blockIdx.x * 128;
  int nout = NOUT[head], ooff = OFFS[head];

  int wid = tid >> 6, lane = tid & 63;
  int wm = wid >> 1, wn = wid & 1;          // 2m x 2n wave grid, wave tile 64px x 128oc
  int l15 = lane & 15, lhi = lane >> 4;

  // A source: thread -> rows r0=tid>>2 and r0+64; SWIZZLED 16B chunk (R18-verified):
  int r0 = tid >> 2;
  int cbsw = (((tid & 3) ^ ((tid >> 3) & 3)) << 4);
  int pA0 = p_loc + r0;       if (pA0 > 39999) pA0 = 39999;
  int pA1 = p_loc + r0 + 64;  if (pA1 > 39999) pA1 = 39999;
  int ay0 = pA0 / 200, ax0 = pA0 - ay0 * 200;
  int ay1 = pA1 / 200, ax1 = pA1 - ay1 * 200;
  const char* xb = (const char*)Xtp + (size_t)b * 40804 * 512;
  const char* As0 = xb + (size_t)((ay0 + 1) * 202 + ax0 + 1) * 512 + cbsw;
  const char* As1 = xb + (size_t)((ay1 + 1) * 202 + ax1 + 1) * 512 + cbsw;

  // B source: rows r0 + {0,64,128,192} of head's W1f, same swizzled chunk
  const char* Bs0 = (const char*)W1f + (size_t)(head * 256 + r0) * 4608 + cbsw;
  const char* Bs1 = Bs0 + (size_t)64 * 4608;
  const char* Bs2 = Bs0 + (size_t)128 * 4608;
  const char* Bs3 = Bs0 + (size_t)192 * 4608;

  // rotating staging buffers
  char* rA = smem;            // read target (tile kt)
  char* rB = smem + 24576;    // tile kt+1
  char* rC = smem + 49152;    // stage target (tile kt+2)

  auto STAGE = [&](int kn, char* dst) {
    int tap = kn >> 3;
    int c0b = (kn & 7) << 6;
    int t3 = tap / 3;
    int doff = (t3 - 1) * 202 + (tap - t3 * 3 - 1);
    long ab = (long)doff * 512 + c0b;
    long bb = (long)kn * 64;
    glds16(As0 + ab, dst + wid * 1024);
    glds16(As1 + ab, dst + wid * 1024 + 4096);
    glds16(Bs0 + bb, dst + 8192 + wid * 1024);
    glds16(Bs1 + bb, dst + 8192 + wid * 1024 + 4096);
    glds16(Bs2 + bb, dst + 8192 + wid * 1024 + 8192);
    glds16(Bs3 + bb, dst + 8192 + wid * 1024 + 12288);
  };

  f32x4 acc[4][8];
#pragma unroll
  for (int mi = 0; mi < 4; ++mi)
#pragma unroll
    for (int ni = 0; ni < 8; ++ni) acc[mi][ni] = (f32x4){0.f, 0.f, 0.f, 0.f};

  // prologue: tiles 0 and 1 in flight (12 loads) — no wait yet
  STAGE(0, rA);
  STAGE(1, rB);

  // frag-read slot swizzle (R18-verified): slot' = lhi ^ ((l15>>1)&3)
  int slotA = (lhi ^ ((l15 >> 1) & 3)) * 8;   // in shorts

  for (int kt = 0; kt < 72; ++kt) {
    // counted wait: tile kt retired (queue at most [kt(6), kt+1(6)])
    if (kt < 71) asm volatile("s_waitcnt vmcnt(6)" ::: "memory");
    else         asm volatile("s_waitcnt vmcnt(0)" ::: "memory");
    __builtin_amdgcn_sched_barrier(0);
    __builtin_amdgcn_s_barrier();          // single barrier: buf(kt) visible to all;
    __builtin_amdgcn_sched_barrier(0);     // also gates restage of buf(kt-1) below

    if (kt < 70) STAGE(kt + 2, rC);        // rC == buffer read at kt-1: safe post-barrier

    const unsigned short* A_sh = (const unsigned short*)rA;
    const unsigned short* B_sh = (const unsigned short*)(rA + 8192);
    short8 af[4], bfr[8];
#pragma unroll
    for (int mi = 0; mi < 4; ++mi) {
      FragU u;
      u.u = *(const us8*)&A_sh[(wm * 64 + mi * 16 + l15) * 32 + slotA];
      af[mi] = u.s;
    }
#pragma unroll
    for (int ni = 0; ni < 8; ++ni) {
      FragU u;
      u.u = *(const us8*)&B_sh[(wn * 128 + ni * 16 + l15) * 32 + slotA];
      bfr[ni] = u.s;
    }
    __builtin_amdgcn_s_setprio(1);
#pragma unroll
    for (int mi = 0; mi < 4; ++mi)
#pragma unroll
      for (int ni = 0; ni < 8; ++ni)
        acc[mi][ni] = __builtin_amdgcn_mfma_f32_16x16x32_bf16(af[mi], bfr[ni], acc[mi][ni], 0, 0, 0);
    __builtin_amdgcn_s_setprio(0);

    char* t = rA; rA = rB; rB = rC; rC = t;
  }

  // ---- epilogue: relu(acc + tb) in fp32 regs; w2 frags from global into regs;
  //      h -> LDS bf16 [128][264]; 1x1 via MFMA (R17/R18-verified indexing).
  {
    float tbr[8];
#pragma unroll
    for (int ni = 0; ni < 8; ++ni) {
      int hc = head * 256 + wn * 128 + ni * 16 + l15;
      float s = gamma[hc] * rsqrtf(var[hc] + 1e-5f);
      tbr[ni] = beta[hc] - s * mean[hc];
    }
#pragma unroll
    for (int mi = 0; mi < 4; ++mi)
#pragma unroll
      for (int ni = 0; ni < 8; ++ni)
#pragma unroll
        for (int r = 0; r < 4; ++r)
          acc[mi][ni][r] = fmaxf(acc[mi][ni][r] + tbr[ni], 0.f);
  }
  short8 wfr[8];
  {
    int jr = (l15 < nout) ? (ooff + l15) : 0;
    const float* wrow = w2 + jr * 256;
#pragma unroll
    for (int kc = 0; kc < 8; ++kc) {
      int koff = kc * 32 + lhi * 8;
      FragU u;
#pragma unroll
      for (int q = 0; q < 8; ++q) u.u[q] = f2bf(wrow[koff + q]);
      wfr[kc] = u.s;
    }
  }
  __syncthreads();   // all waves done with last tile's frag reads before h_s overwrite
#pragma unroll
  for (int mi = 0; mi < 4; ++mi) {
#pragma unroll
    for (int ni = 0; ni < 8; ++ni) {
      int ocl = wn * 128 + ni * 16 + l15;
#pragma unroll
      for (int r = 0; r < 4; ++r) {
        int px = wm * 64 + mi * 16 + lhi * 4 + r;
        h_s[px * 264 + ocl] = f2bf(acc[mi][ni][r]);
      }
    }
  }
  __syncthreads();

#pragma unroll
  for (int g2 = 0; g2 < 2; ++g2) {
    int grp = wid * 2 + g2;
    float b2v = (l15 < nout) ? b2[ooff + l15] : 0.f;
    f32x4 oacc = (f32x4){0.f, 0.f, 0.f, 0.f};
#pragma unroll
    for (int kc = 0; kc < 8; ++kc) {
      int koff = kc * 32 + lhi * 8;
      FragU hu;
      hu.u = *(const us8*)&h_s[(grp * 16 + l15) * 264 + koff];
      oacc = __builtin_amdgcn_mfma_f32_16x16x32_bf16(hu.s, wfr[kc], oacc, 0, 0, 0);
    }
    if (l15 < nout) {
      float* dst = out + (size_t)(b * 29 + ooff + l15) * 40000;
#pragma unroll
      for (int r = 0; r < 4; ++r) {
        int px_g = p_loc + grp * 16 + lhi * 4 + r;
        if (px_g < 40000) dst[px_g] = oacc[r] + b2v;
      }
    }
  }
}

// ---------------- FALLBACK (R10-proven, no ws): B folded in-kernel from w1
__global__ __launch_bounds__(512) void conv_head_nows_k(
    const float* __restrict__ sf, const float* __restrict__ w1,
    const float* __restrict__ gamma, const float* __restrict__ beta,
    const float* __restrict__ mean, const float* __restrict__ var,
    const float* __restrict__ w2, const float* __restrict__ b2,
    float* __restrict__ out) {
  const int NOUT[6] = {4, 2, 1, 3, 2, 2};
  const int OFFS[6] = {0, 4, 6, 7, 10, 12};
  __shared__ __align__(16) char smem[78080];
  unsigned short* A_s  = (unsigned short*)smem;
  unsigned short* B_s  = (unsigned short*)(smem + 9216);
  unsigned short* h_s  = (unsigned short*)smem;
  unsigned short* w2_s = (unsigned short*)(smem + 67584);
  float* tb_s          = (float*)(smem + 76032);
  float* s_s           = (float*)(smem + 77056);

  int tid = threadIdx.x;
  int head = blockIdx.z, b = blockIdx.y;
  int p_loc = blockIdx.x * 128;
  int nout = NOUT[head], ooff = OFFS[head];
  {
    int j = tid >> 5, c8 = (tid & 31) * 8;
    us8 t;
#pragma unroll
    for (int q = 0; q < 8; ++q)
      t[q] = (j < nout) ? f2bf(w2[(ooff + j) * 256 + c8 + q]) : (unsigned short)0;
    *(us8*)&w2_s[j * 264 + c8] = t;
  }
  if (tid < 256) {
    int hc = head * 256 + tid;
    float s = gamma[hc] * rsqrtf(var[hc] + 1e-5f);
    s_s[tid] = s;
    tb_s[tid] = beta[hc] - s * mean[hc];
  }
  __syncthreads();

  int wid = tid >> 6, lane = tid & 63;
  int wm = wid >> 2, wn = wid & 3;
  int l15 = lane & 15, lhi = lane >> 4;
  int cg = wid, mm = lane;
  int p0 = p_loc + mm, p1 = p0 + 64;
  int ay0 = p0 / 200, ax0 = p0 - ay0 * 200;
  int ay1 = p1 / 200, ax1 = p1 - ay1 * 200;
  const float* sfb = sf + (size_t)b * 256 * 40000;
  int oc = tid >> 1, half = tid & 1;
  const float* w1h = w1 + ((size_t)head * 256 + oc) * 2304;
  float sv = s_s[oc];

  f32x4 acc[4][4];
#pragma unroll
  for (int mi = 0; mi < 4; ++mi)
#pragma unroll
    for (int ni = 0; ni < 4; ++ni) acc[mi][ni] = (f32x4){0.f, 0.f, 0.f, 0.f};

  for (int kt = 0; kt < 72; ++kt) {
    int tap = kt >> 3;
    int c0 = (kt & 7) << 5;
    int t3 = tap / 3;
    int dy = t3 - 1, dx = tap - t3 * 3 - 1;
    {
      const float* src = sfb + (size_t)(c0 + cg * 4) * 40000;
      int yy = ay0 + dy, xx = ax0 + dx;
      us4 v = (us4){0, 0, 0, 0};
      if ((unsigned)yy < 200u && (unsigned)xx < 200u) {
        int pix = yy * 200 + xx;
        v[0] = f2bf(src[pix]);
        v[1] = f2bf(src[40000 + pix]);
        v[2] = f2bf(src[80000 + pix]);
        v[3] = f2bf(src[120000 + pix]);
      }
      *(us4*)&A_s[mm * 36 + cg * 4] = v;
      yy = ay1 + dy; xx = ax1 + dx;
      us4 w = (us4){0, 0, 0, 0};
      if ((unsigned)yy < 200u && (unsigned)xx < 200u) {
        int pix = yy * 200 + xx;
        w[0] = f2bf(src[pix]);
        w[1] = f2bf(src[40000 + pix]);
        w[2] = f2bf(src[80000 + pix]);
        w[3] = f2bf(src[120000 + pix]);
      }
      *(us4*)&A_s[(mm + 64) * 36 + cg * 4] = w;
    }
    {
      int kk = half * 16;
#pragma unroll
      for (int g = 0; g < 4; ++g) {
        us4 t;
#pragma unroll
        for (int q = 0; q < 4; ++q)
          t[q] = f2bf(sv * w1h[(c0 + kk + g * 4 + q) * 9 + tap]);
        *(us4*)&B_s[oc * 36 + kk + g * 4] = t;
      }
    }
    __syncthreads();
    short8 af[4], bfr[4];
#pragma unroll
    for (int mi = 0; mi < 4; ++mi) {
      int a = (wm * 64 + mi * 16 + l15) * 36 + lhi * 8;
      FragU u;
      u.h[0] = *(const us4*)&A_s[a];
      u.h[1] = *(const us4*)&A_s[a + 4];
      af[mi] = u.s;
    }
#pragma unroll
    for (int ni = 0; ni < 4; ++ni) {
      int a = (wn * 64 + ni * 16 + l15) * 36 + lhi * 8;
      FragU u;
      u.h[0] = *(const us4*)&B_s[a];
      u.h[1] = *(const us4*)&B_s[a + 4];
      bfr[ni] = u.s;
    }
#pragma unroll
    for (int mi = 0; mi < 4; ++mi)
#pragma unroll
      for (int ni = 0; ni < 4; ++ni)
        acc[mi][ni] = __builtin_amdgcn_mfma_f32_16x16x32_bf16(af[mi], bfr[ni], acc[mi][ni], 0, 0, 0);
    __syncthreads();
  }
#pragma unroll
  for (int mi = 0; mi < 4; ++mi) {
#pragma unroll
    for (int ni = 0; ni < 4; ++ni) {
      int ocl = wn * 64 + ni * 16 + l15;
      float tbv = tb_s[ocl];
#pragma unroll
      for (int r = 0; r < 4; ++r) {
        int px = wm * 64 + mi * 16 + lhi * 4 + r;
        float v = fmaxf(acc[mi][ni][r] + tbv, 0.f);
        h_s[px * 264 + ocl] = f2bf(v);
      }
    }
  }
  __syncthreads();
  {
    int j = l15;
    float b2v = (j < nout) ? b2[ooff + j] : 0.f;
    f32x4 oacc = (f32x4){0.f, 0.f, 0.f, 0.f};
#pragma unroll
    for (int kc = 0; kc < 8; ++kc) {
      int koff = kc * 32 + lhi * 8;
      FragU hu, wu;
      hu.u = *(const us8*)&h_s[(wid * 16 + l15) * 264 + koff];
      wu.u = *(const us8*)&w2_s[l15 * 264 + koff];
      oacc = __builtin_amdgcn_mfma_f32_16x16x32_bf16(hu.s, wu.s, oacc, 0, 0, 0);
    }
    if (j < nout) {
      float* dst = out + (size_t)(b * 29 + ooff + j) * 40000;
#pragma unroll
      for (int r = 0; r < 4; ++r) {
        int px_g = p_loc + wid * 16 + lhi * 4 + r;
        if (px_g < 40000) dst[px_g] = oacc[r] + b2v;
      }
    }
  }
}

// ---------------- targets: heatmap + zero scalar channels (validated)
__global__ void heat_k(const float* __restrict__ gt, float* __restrict__ out) {
  __shared__ float bx[128], by[128], binv[128];
  __shared__ int bcls[128];
  int b = blockIdx.y, tid = threadIdx.x;
  if (tid < 128) {
    const float* g = gt + (b * 128 + tid) * 10;
    float x = g[0], y = g[1], z = g[2];
    bool valid = fabsf(x) + fabsf(y) + fabsf(z) > 0.f;
    float gx = x / 0.1f;
    float gy = (y + 39.68f) / 0.1f;
    float fx = floorf(gx), fy = floorf(gy);
    int gxi = (int)fx, gyi = (int)fy;
    valid = valid && gxi >= 0 && gxi < 200 && gyi >= 0 && gyi < 200;
    float bw = g[3], bl = g[4];
    float sigma = fmaxf(sqrtf(bw * bw + bl * bl) * 0.5f, 2.0f) / 3.0f;
    binv[tid] = valid ? 1.f / (2.f * sigma * sigma) : -1.f;
    bx[tid] = fx;
    by[tid] = fy;
    bcls[tid] = min(max((int)g[7], 0), 3);
  }
  __syncthreads();
  int pid = blockIdx.x * 256 + tid;
  if (pid >= 40000) return;
  float py = (float)(pid / 200);
  float px = (float)(pid - (pid / 200) * 200);
  float h0 = 0.f, h1 = 0.f, h2 = 0.f, h3 = 0.f;
  for (int n = 0; n < 128; ++n) {
    float inv = binv[n];
    if (inv < 0.f) continue;
    float ddx = px - bx[n], ddy = py - by[n];
    float t = (ddx * ddx + ddy * ddy) * inv;
    if (t > 40.f) continue;
    float e = __expf(-t);
    int c = bcls[n];
    h0 = fmaxf(h0, c == 0 ? e : 0.f);
    h1 = fmaxf(h1, c == 1 ? e : 0.f);
    h2 = fmaxf(h2, c == 2 ? e : 0.f);
    h3 = fmaxf(h3, c == 3 ? e : 0.f);
  }
  int base = (b * 29 + 14) * 40000 + pid;
  out[base] = h0;
  out[base + 40000] = h1;
  out[base + 80000] = h2;
  out[base + 120000] = h3;
#pragma unroll
  for (int q = 0; q < 11; ++q) out[base + (4 + q) * 40000] = 0.f;
}

// ---------------- targets: serial per-batch scatter (validated)
__global__ void scatter_k(const float* __restrict__ gt, float* __restrict__ out) {
  int b = threadIdx.x;
  if (b >= 4) return;
  for (int n = 0; n < 128; ++n) {
    const float* g = gt + (b * 128 + n) * 10;
    float x = g[0], y = g[1], z = g[2];
    if (!(fabsf(x) + fabsf(y) + fabsf(z) > 0.f)) continue;
    float gx = x / 0.1f;
    float gy = (y + 39.68f) / 0.1f;
    float fx = floorf(gx), fy = floorf(gy);
    int gxi = (int)fx, gyi = (int)fy;
    if (gxi < 0 || gxi >= 200 || gyi < 0 || gyi >= 200) continue;
    int base = (b * 29 + 18) * 40000 + gyi * 200 + gxi;
    out[base] = gx - fx;
    out[base + 1 * 40000] = gy - fy;
    out[base + 2 * 40000] = z;
    out[base + 3 * 40000] = g[3];
    out[base + 4 * 40000] = g[4];
    out[base + 5 * 40000] = g[5];
    out[base + 6 * 40000] = sinf(g[6]);
    out[base + 7 * 40000] = cosf(g[6]);
    out[base + 8 * 40000] = g[8];
    out[base + 9 * 40000] = g[9];
    out[base + 10 * 40000] = 1.f;
  }
}

extern "C" void kernel_launch(void* const* d_in, const int* in_sizes, int n_in,
                              void* d_out, int out_size, void* d_ws, size_t ws_size,
                              hipStream_t stream) {
  const float* sf    = (const float*)d_in[0];
  const float* gt    = (const float*)d_in[1];
  const float* w1    = (const float*)d_in[2];
  const float* gamma = (const float*)d_in[3];
  const float* beta  = (const float*)d_in[4];
  const float* mean  = (const float*)d_in[5];
  const float* var   = (const float*)d_in[6];
  const float* w2    = (const float*)d_in[7];
  const float* b2    = (const float*)d_in[8];
  float* out = (float*)d_out;
  char* ws = (char*)d_ws;

  const size_t W1F_BYTES = (size_t)6 * 256 * 2304 * 2;        //  7,077,888
  const size_t XTP_BYTES = (size_t)4 * 40804 * 256 * 2;       // 83,566,592
  unsigned short* W1f = (unsigned short*)ws;

  dim3 cgrid(313, 4, 6);
  if (ws_size >= W1F_BYTES + XTP_BYTES) {
    unsigned short* Xtp = (unsigned short*)(ws + W1F_BYTES);
    prep_w1f_k<<<(6 * 256 * 2304 + 255) / 256, 256, 0, stream>>>(w1, gamma, var, W1f);
    border_zero_k<<<(4 * 804 * 32 + 255) / 256, 256, 0, stream>>>(Xtp);
    transpose_pad_k<<<dim3(1250, 8, 4), dim3(32, 8), 0, stream>>>(sf, Xtp);
    conv_head_v6_k<<<cgrid, 256, 0, stream>>>(Xtp, W1f, gamma, beta, mean, var, w2, b2, out);
  } else {
    conv_head_nows_k<<<cgrid, 512, 0, stream>>>(sf, w1, gamma, beta, mean, var, w2, b2, out);
  }
  heat_k<<<dim3(157, 4), 256, 0, stream>>>(gt, out);
  scatter_k<<<1, 64, 0, stream>>>(gt, out);
}